// Round 1
// 105.721 us; speedup vs baseline: 1.0503x; 1.0503x over previous
//
#include <hip/hip_runtime.h>
#include <hip/hip_bf16.h>
#include <stdint.h>

typedef __attribute__((ext_vector_type(8))) short short8;
typedef __attribute__((ext_vector_type(4))) float floatx4;
typedef __attribute__((ext_vector_type(4))) int intx4;

// ---------------------------------------------------------------------------
// Threefry-2x32 (20 rounds), bit-exact vs JAX (verified r2: absmax 0.0).
// ---------------------------------------------------------------------------
__device__ __forceinline__ void threefry2x32(uint32_t k0, uint32_t k1,
                                             uint32_t& x0, uint32_t& x1) {
  const uint32_t ks2 = k0 ^ k1 ^ 0x1BD11BDAu;
  uint32_t ks[3] = {k0, k1, ks2};
  const int rot[8] = {13, 15, 26, 6, 17, 29, 16, 24};
  x0 += ks[0];
  x1 += ks[1];
#pragma unroll
  for (int i = 0; i < 5; ++i) {
#pragma unroll
    for (int j = 0; j < 4; ++j) {
      const int r = rot[(i & 1) * 4 + j];
      x0 += x1;
      x1 = (x1 << r) | (x1 >> (32 - r));
      x1 ^= x0;
    }
    x0 += ks[(i + 1) % 3];
    x1 += ks[(i + 2) % 3] + (uint32_t)(i + 1);
  }
}

__device__ __forceinline__ float dropmask(int core, int e, float v) {
  uint32_t f0 = 0u, f1 = (uint32_t)core;
  threefry2x32(0u, 42u, f0, f1);
  uint32_t a = 0u, b = (uint32_t)e;
  threefry2x32(f0, f1, a, b);
  uint32_t bits = a ^ b;
  float u = __uint_as_float((bits >> 9) | 0x3F800000u) - 1.0f;
  float m = (u < 0.8f) ? 1.0f : 0.0f;
  return v * m / 0.8f;
}

__device__ __forceinline__ unsigned short f2bf(float f) {  // RNE
  uint32_t u = __float_as_uint(f);
  uint32_t r = u + 0x7fffu + ((u >> 16) & 1u);
  return (unsigned short)(r >> 16);
}

union B2I { __hip_bfloat162 b; int i; };
__device__ __forceinline__ int pk_bf16(float lo, float hi) {
  B2I u;
  u.b = __float22bfloat162_rn(make_float2(lo, hi));
  return u.i;
}
union Frag { intx4 i; short8 s; };

// ---------------------------------------------------------------------------
// Prep: masked bf16 B matrices, pre-swizzled into MFMA B-fragment order
// (verified r3-r7). stage1: k = c*32+q*8+j (c<16). stage2: t=45q+c, m=t/5,
// nk=8*(t%5)+j (c<45, K'=1440, zeros for nk>=36 or invalid col).
// ALSO: initializes out = bias (fused kernel accumulates via atomicAdd; same
// stream ordering guarantees this runs first each iteration).
// ---------------------------------------------------------------------------
__global__ void prep_kernel(const float* __restrict__ eps0,
                            const float* __restrict__ eps1,
                            unsigned short* __restrict__ bsw1,
                            unsigned short* __restrict__ bsw2,
                            const float* __restrict__ bias,
                            float* __restrict__ out) {
  int idx = blockIdx.x * 256 + threadIdx.x;  // grid exactly 31232
  if (idx < 1280) out[idx] = bias[idx % 10]; // (128,10) = bias init
  if (idx < 8192) {
    int j = idx & 7, L = (idx >> 3) & 63, c = idx >> 9;
    int o = L & 15, q = L >> 4;
    int k = c * 32 + q * 8 + j;
    float v = 0.0f;
    if (o < 6) {
      int e = o * 512 + k;
      v = dropmask(0, e, eps0[e]);
    }
    bsw1[idx] = f2bf(v);
  } else {
    int t2 = idx - 8192;  // < 23040 = 45*512
    int j = t2 & 7, L = (t2 >> 3) & 63, c = t2 >> 9;
    int o = L & 15, q = L >> 4;
    int t = 45 * q + c;
    int m = t / 5, nk = 8 * (t % 5) + j;
    float v = 0.0f;
    if (o < 10 && nk < 36) {
      int e = o * 1296 + m * 36 + nk;
      v = dropmask(1, e, eps1[e]);
    }
    bsw2[t2] = f2bf(v);
  }
}

// 6-way select, cndmask chain (runtime k, constant element indices)
__device__ __forceinline__ float sel6(const float a[6], int k) {
  float r = a[0];
  r = (k == 1) ? a[1] : r;
  r = (k == 2) ? a[2] : r;
  r = (k == 3) ? a[3] : r;
  r = (k == 4) ? a[4] : r;
  r = (k == 5) ? a[5] : r;
  return r;
}

// ---------------------------------------------------------------------------
// Fused kernel: 4 blocks (512 thr each) per batch image; block handles a
// row-chunk of the image (stage-2 rows {0-6,7-12,13-18,19-24}, stage-1 rows
// with +1 halo). h and flat chunks live in LDS (~12 KB). Linear: each block
// dots its flat slice against the matching W column slice, atomicAdd's 10
// partials into out (pre-initialized to bias by prep_kernel).
// ---------------------------------------------------------------------------
__global__ __launch_bounds__(512, 2) void fused_kernel(
    const float* __restrict__ x, const unsigned short* __restrict__ bsw1,
    const unsigned short* __restrict__ bsw2, const float* __restrict__ W,
    float* __restrict__ out) {
  __shared__ float h_lds[1248];     // up to 8*26*6
  __shared__ float flat_lds[1750];  // up to 7*25*10
  __shared__ float red[8][10];

  const int bid = blockIdx.x;       // grid exactly 512
  const int b = bid >> 2;           // image
  const int ck = bid & 3;           // row-chunk
  const int r0 = ck ? 6 * ck + 1 : 0;      // first stage-2 output row
  const int rows2 = ck ? 6 : 7;            // stage-2 rows in this chunk
  const int hrows = rows2 + 1;             // h rows needed (halo)
  const int n1 = hrows * 26;               // stage-1 pixels (208 or 182)
  const int tiles1 = (n1 + 15) >> 4;       // 13 or 12
  const int n2 = rows2 * 25;               // stage-2 pixels (175 or 150)
  const int tiles2 = (n2 + 15) >> 4;       // 11 or 10

  const int tid = threadIdx.x;
  const int lane = tid & 63;
  const int wv = tid >> 6;  // 0..7
  const int col = lane & 15, q = lane >> 4;

  // ---- B1 fragments -> registers (64 VGPR) ----
  intx4 bfr1[16];
  const intx4* bsrc1 = (const intx4*)bsw1;
#pragma unroll
  for (int c = 0; c < 16; ++c) bfr1[c] = bsrc1[c * 64 + lane];

  // ---- Stage 1: tiles of 16 pixels over this chunk's h rows ----
  const float2* x2 = (const float2*)x + b * 784;  // 28*28 float2 per image
#pragma unroll 1
  for (int tile = wv; tile < tiles1; tile += 8) {
    const int p_raw = tile * 16 + col;
    const int p = p_raw < n1 ? p_raw : n1 - 1;  // clamp for addressing
    const int il = p / 26, jj = p - il * 26;
    const int ii = r0 + il;

    float xv[9][2];
#pragma unroll
    for (int di = 0; di < 3; ++di)
#pragma unroll
      for (int dj = 0; dj < 3; ++dj) {
        float2 v = x2[(ii + di) * 28 + (jj + dj)];
        xv[di * 3 + dj][0] = v.x;
        xv[di * 3 + dj][1] = v.y;
      }

    float w3[8];
#pragma unroll
    for (int j = 0; j < 8; ++j)
      w3[j] = xv[6][(j >> 2) & 1] * xv[7][(j >> 1) & 1] * xv[8][j & 1];

    const float wq = xv[4][(q >> 1) & 1] * xv[5][q & 1];
    float t01[4], t23[4];
#pragma unroll
    for (int a = 0; a < 2; ++a)
#pragma unroll
      for (int d = 0; d < 2; ++d) {
        t01[a * 2 + d] = xv[0][a] * xv[1][d];
        t23[a * 2 + d] = xv[2][a] * xv[3][d] * wq;
      }

    floatx4 acc0 = {0.f, 0.f, 0.f, 0.f};
    floatx4 acc1 = {0.f, 0.f, 0.f, 0.f};
#pragma unroll
    for (int c = 0; c < 16; ++c) {
      Frag bf;
      bf.i = bfr1[c];
      const float w = t01[c >> 2] * t23[c & 3];
      Frag af;
      af.i.x = pk_bf16(w * w3[0], w * w3[1]);
      af.i.y = pk_bf16(w * w3[2], w * w3[3]);
      af.i.z = pk_bf16(w * w3[4], w * w3[5]);
      af.i.w = pk_bf16(w * w3[6], w * w3[7]);
      if (c & 1)
        acc1 = __builtin_amdgcn_mfma_f32_16x16x32_bf16(af.s, bf.s, acc1, 0, 0, 0);
      else
        acc0 = __builtin_amdgcn_mfma_f32_16x16x32_bf16(af.s, bf.s, acc0, 0, 0, 0);
    }
    const floatx4 acc = acc0 + acc1;
    if (col < 6) {
#pragma unroll
      for (int r = 0; r < 4; ++r) {
        const int pp = tile * 16 + q * 4 + r;
        if (pp < n1) h_lds[pp * 6 + col] = acc[r];
      }
    }
  }

  // ---- B2 fragments -> registers (bfr1 dead, regs reused) ----
  intx4 bfr2[45];
  const intx4* bsrc2 = (const intx4*)bsw2;
#pragma unroll
  for (int c = 0; c < 45; ++c) bfr2[c] = bsrc2[c * 64 + lane];

  __syncthreads();  // h_lds complete

  // ---- Stage 2: tiles of 16 pixels over this chunk's output rows ----
#pragma unroll 1
  for (int tile = wv; tile < tiles2; tile += 8) {
    const int p_raw = tile * 16 + col;
    const int p = p_raw < n2 ? p_raw : n2 - 1;  // clamp for addressing
    const int il = p / 25, jj = p - il * 25;
    const int hbase = (il * 26 + jj) * 6;       // local h row == local out row

    float h00[6], h01[6], h10[6], h11[6];
#pragma unroll
    for (int t = 0; t < 6; ++t) {
      h00[t] = h_lds[hbase + t];
      h01[t] = h_lds[hbase + 6 + t];
      h10[t] = h_lds[hbase + 156 + t];
      h11[t] = h_lds[hbase + 162 + t];
    }

    floatx4 acc0 = {0.f, 0.f, 0.f, 0.f};
    floatx4 acc1 = {0.f, 0.f, 0.f, 0.f};
#pragma unroll
    for (int d = 0; d < 9; ++d) {  // chunk c = 5d + e; m = 9q + d
      const int m = 9 * q + d;
      const int ia = (m * 43) >> 8;  // m/6 exact for m < 54
      const int ic = m - ia * 6;
      const float p01 = sel6(h00, ia) * sel6(h01, ic);
      float ph[6];
#pragma unroll
      for (int a = 0; a < 6; ++a) ph[a] = p01 * h10[a];
#pragma unroll
      for (int e = 0; e < 5; ++e) {
        Frag bf;
        bf.i = bfr2[d * 5 + e];
        const int n0 = 8 * e;
        float av[8];
#pragma unroll
        for (int j = 0; j < 8; ++j) {
          const int n = n0 + j;  // compile-time after unroll
          av[j] = (n < 36) ? ph[n / 6] * h11[n % 6] : 0.0f;
        }
        Frag af;
        af.i.x = pk_bf16(av[0], av[1]);
        af.i.y = pk_bf16(av[2], av[3]);
        af.i.z = pk_bf16(av[4], av[5]);
        af.i.w = pk_bf16(av[6], av[7]);
        if (e & 1)
          acc1 = __builtin_amdgcn_mfma_f32_16x16x32_bf16(af.s, bf.s, acc1, 0, 0, 0);
        else
          acc0 = __builtin_amdgcn_mfma_f32_16x16x32_bf16(af.s, bf.s, acc0, 0, 0, 0);
      }
    }
    const floatx4 acc = acc0 + acc1;
    if (col < 10) {
#pragma unroll
      for (int r = 0; r < 4; ++r) {
        const int pp = tile * 16 + q * 4 + r;
        if (pp < n2) flat_lds[pp * 10 + col] = acc[r];
      }
    }
  }
  __syncthreads();  // flat_lds complete

  // ---- Linear (chunk slice): global flat index = r0*250 + local index ----
  const float* Wc = W + r0 * 250;
  const int nf = n2 * 10;  // 1750 or 1500
  float acc[10];
#pragma unroll
  for (int o = 0; o < 10; ++o) acc[o] = 0.0f;
  for (int f = tid; f < nf; f += 512) {
    const float v = flat_lds[f];
#pragma unroll
    for (int o = 0; o < 10; ++o) acc[o] += v * Wc[o * 6250 + f];
  }
#pragma unroll
  for (int o = 0; o < 10; ++o) {
#pragma unroll
    for (int s = 32; s > 0; s >>= 1) acc[o] += __shfl_xor(acc[o], s, 64);
  }
  if (lane == 0) {
#pragma unroll
    for (int o = 0; o < 10; ++o) red[wv][o] = acc[o];
  }
  __syncthreads();
  if (tid < 10) {
    float r = 0.0f;
#pragma unroll
    for (int ww = 0; ww < 8; ++ww) r += red[ww][tid];
    atomicAdd(&out[b * 10 + tid], r);  // out pre-set to bias by prep_kernel
  }
}

// ---------------------------------------------------------------------------
extern "C" void kernel_launch(void* const* d_in, const int* in_sizes, int n_in,
                              void* d_out, int out_size, void* d_ws,
                              size_t ws_size, hipStream_t stream) {
  const float* x = (const float*)d_in[0];     // (128,28,28,2)
  const float* eps0 = (const float*)d_in[1];  // (6,512)
  const float* eps1 = (const float*)d_in[2];  // (10,1296)
  const float* W = (const float*)d_in[3];     // (10,6250)
  const float* bias = (const float*)d_in[4];  // (10,)
  float* out = (float*)d_out;                 // (128,10)

  char* wsb = (char*)d_ws;
  unsigned short* bsw1 = (unsigned short*)wsb;            // 16384 B
  unsigned short* bsw2 = (unsigned short*)(wsb + 16384);  // 46080 B

  hipLaunchKernelGGL(prep_kernel, dim3(122), dim3(256), 0, stream, eps0, eps1,
                     bsw1, bsw2, bias, out);
  hipLaunchKernelGGL(fused_kernel, dim3(512), dim3(512), 0, stream, x, bsw1,
                     bsw2, W, out);
}